// Round 2
// baseline (698.337 us; speedup 1.0000x reference)
//
#include <hip/hip_runtime.h>

#define T_LEN 512
#define BATCH 64

__device__ __forceinline__ float fast_sigmoid(float x) {
    // 1/(1+exp(-x)) via v_exp + v_rcp (rel err ~1e-6, threshold is 4.8e-2)
    return __builtin_amdgcn_rcpf(1.0f + __expf(-x));
}

// ---------------------------------------------------------------------------
// Kernel A: per-(b,t) precompute of sensory w_num / w_den  [B*T, 32] each
// ---------------------------------------------------------------------------
__global__ __launch_bounds__(256, 1) void sensory_precompute_kernel(
    const float* __restrict__ x,        // [B,T,6]
    const float* __restrict__ mean_us,  // [6]
    const float* __restrict__ std_us,   // [6]
    const float* __restrict__ pre_w1,   // [6,32]
    const float* __restrict__ pre_b1,   // [32]
    const float* __restrict__ pre_w2,   // [32,16]
    const float* __restrict__ pre_b2,   // [16]
    const float* __restrict__ input_w,  // [16]
    const float* __restrict__ input_b,  // [16]
    const float* __restrict__ s_mu,     // [16,32]
    const float* __restrict__ s_sigma,  // [16,32]
    const float* __restrict__ s_w,      // [16,32]
    const float* __restrict__ s_erev,   // [16,32]
    float* __restrict__ wns_out,        // [B*T,32]
    float* __restrict__ wds_out,        // [B*T,32]
    int total)
{
    const int idx = blockIdx.x * blockDim.x + threadIdx.x;
    if (idx >= total) return;

    const float* xp = x + (size_t)idx * 6;
    float xn[6];
    #pragma unroll
    for (int d = 0; d < 6; ++d)
        xn[d] = (xp[d] - mean_us[d]) / std_us[d];

    // 6 -> 32 + GELU(tanh approx, matches jax.nn.gelu default)
    float f1[32];
    #pragma unroll
    for (int h = 0; h < 32; ++h) {
        float a = pre_b1[h];
        #pragma unroll
        for (int d = 0; d < 6; ++d)
            a = fmaf(xn[d], pre_w1[d * 32 + h], a);
        // gelu(a) = a * sigmoid(2*sqrt(2/pi)*(a + 0.044715 a^3))
        const float y2 = 1.5957691216057308f * fmaf(0.044715f * a * a, a, a);
        f1[h] = a * fast_sigmoid(y2);
    }

    float wn[32], wd[32];
    #pragma unroll
    for (int u = 0; u < 32; ++u) { wn[u] = 0.0f; wd[u] = 0.0f; }

    // 32 -> 16, input map, then 16x32 sensory synapses, reduce over s
    for (int s = 0; s < 16; ++s) {
        float a = pre_b2[s];
        #pragma unroll
        for (int h = 0; h < 32; ++h)
            a = fmaf(f1[h], pre_w2[h * 16 + s], a);
        const float fs = fmaf(a, input_w[s], input_b[s]);
        #pragma unroll
        for (int u = 0; u < 32; ++u) {
            const int o = s * 32 + u;
            const float sact =
                s_w[o] * fast_sigmoid(s_sigma[o] * (fs - s_mu[o]));
            wn[u] = fmaf(sact, s_erev[o], wn[u]);
            wd[u] += sact;
        }
    }

    float* wno = wns_out + (size_t)idx * 32;
    float* wdo = wds_out + (size_t)idx * 32;
    #pragma unroll
    for (int u = 0; u < 32; ++u) { wno[u] = wn[u]; wdo[u] = wd[u]; }
}

// ---------------------------------------------------------------------------
// Kernel B: sequential LTC scan. One wave (64 lanes) per batch element.
// lane l: post-unit u = l&31, pre-half h = l>>5 (16 pre units each).
// All 32x32 synapse params live in VGPRs (4x16 per lane).
// ---------------------------------------------------------------------------
__global__ __launch_bounds__(64, 1) void ltc_scan_kernel(
    const float* __restrict__ wns_all,  // [B*T,32]
    const float* __restrict__ wds_all,  // [B*T,32]
    const float* __restrict__ mu,       // [32,32]  (pre, post)
    const float* __restrict__ sigma,    // [32,32]
    const float* __restrict__ w,        // [32,32]
    const float* __restrict__ erev,     // [32,32]
    const float* __restrict__ gleak,    // [32]
    const float* __restrict__ vleak,    // [32]
    const float* __restrict__ cm,       // [32]
    const float* __restrict__ output_w, // [3]
    const float* __restrict__ output_b, // [3]
    const float* __restrict__ mean_us,  // [6]
    const float* __restrict__ std_us,   // [6]
    float* __restrict__ out)            // [B,T,3]
{
    const int b = blockIdx.x;
    const int lane = threadIdx.x;
    const int u = lane & 31;
    const int pbase = (lane >> 5) << 4;  // 0 or 16

    float mu_r[16], sg_r[16], w_r[16], we_r[16];
    #pragma unroll
    for (int i = 0; i < 16; ++i) {
        const int o = (pbase + i) * 32 + u;
        mu_r[i] = mu[o];
        sg_r[i] = sigma[o];
        w_r[i]  = w[o];
        we_r[i] = w_r[i] * erev[o];
    }
    const float cmt  = cm[u] * 3.0f;         // cm * ODE_UNFOLDS
    const float gl   = gleak[u];
    const float glvl = gl * vleak[u];

    // fused output affine: out = (v*ow+ob)*std + mean = v*osc + osh
    float osc = 0.0f, osh = 0.0f;
    if (lane < 3) {
        const float sd = std_us[lane];
        osc = output_w[lane] * sd;
        osh = fmaf(output_b[lane], sd, mean_us[lane]);
    }

    const float* wns_b = wns_all + ((size_t)b * T_LEN) * 32;
    const float* wds_b = wds_all + ((size_t)b * T_LEN) * 32;
    float* out_b = out + ((size_t)b * T_LEN) * 3;

    float v = 0.0f;
    float wns = wns_b[u];
    float wds = wds_b[u];

    for (int t = 0; t < T_LEN; ++t) {
        // software prefetch next timestep's sensory currents
        float wns_n = 0.0f, wds_n = 0.0f;
        if (t + 1 < T_LEN) {
            wns_n = wns_b[(t + 1) * 32 + u];
            wds_n = wds_b[(t + 1) * 32 + u];
        }

        #pragma unroll
        for (int k = 0; k < 3; ++k) {
            float sig[16];
            #pragma unroll
            for (int i = 0; i < 16; ++i) {
                const float vp = __shfl(v, pbase + i, 64);  // v of pre-unit
                sig[i] = fast_sigmoid(sg_r[i] * (vp - mu_r[i]));
            }
            float wn0 = 0.f, wn1 = 0.f, wd0 = 0.f, wd1 = 0.f;
            #pragma unroll
            for (int i = 0; i < 16; i += 2) {
                wn0 = fmaf(we_r[i],     sig[i],     wn0);
                wd0 = fmaf(w_r[i],      sig[i],     wd0);
                wn1 = fmaf(we_r[i + 1], sig[i + 1], wn1);
                wd1 = fmaf(w_r[i + 1],  sig[i + 1], wd1);
            }
            float wnum = wn0 + wn1;
            float wden = wd0 + wd1;
            // combine the two pre-halves (lane <-> lane^32)
            wnum += __shfl_xor(wnum, 32, 64);
            wden += __shfl_xor(wden, 32, 64);

            const float num = fmaf(cmt, v, glvl + wnum + wns);
            const float den = cmt + gl + wden + wds + 1e-8f;
            v = num * __builtin_amdgcn_rcpf(den);
        }

        if (lane < 3)
            out_b[t * 3 + lane] = fmaf(v, osc, osh);

        wns = wns_n;
        wds = wds_n;
    }
}

// ---------------------------------------------------------------------------
extern "C" void kernel_launch(void* const* d_in, const int* in_sizes, int n_in,
                              void* d_out, int out_size, void* d_ws, size_t ws_size,
                              hipStream_t stream) {
    const float* x        = (const float*)d_in[0];
    const float* mean_us  = (const float*)d_in[1];
    const float* std_us   = (const float*)d_in[2];
    const float* pre_w1   = (const float*)d_in[3];
    const float* pre_b1   = (const float*)d_in[4];
    const float* pre_w2   = (const float*)d_in[5];
    const float* pre_b2   = (const float*)d_in[6];
    const float* input_w  = (const float*)d_in[7];
    const float* input_b  = (const float*)d_in[8];
    const float* s_mu     = (const float*)d_in[9];
    const float* s_sigma  = (const float*)d_in[10];
    const float* s_w      = (const float*)d_in[11];
    const float* s_erev   = (const float*)d_in[12];
    const float* mu       = (const float*)d_in[13];
    const float* sigma    = (const float*)d_in[14];
    const float* w        = (const float*)d_in[15];
    const float* erev     = (const float*)d_in[16];
    const float* gleak    = (const float*)d_in[17];
    const float* vleak    = (const float*)d_in[18];
    const float* cm       = (const float*)d_in[19];
    const float* output_w = (const float*)d_in[20];
    const float* output_b = (const float*)d_in[21];

    const int total = BATCH * T_LEN;  // 32768

    float* wns = (float*)d_ws;                       // [B*T,32]
    float* wds = wns + (size_t)total * 32;           // [B*T,32]  (16 MB total)

    sensory_precompute_kernel<<<(total + 255) / 256, 256, 0, stream>>>(
        x, mean_us, std_us, pre_w1, pre_b1, pre_w2, pre_b2,
        input_w, input_b, s_mu, s_sigma, s_w, s_erev,
        wns, wds, total);

    ltc_scan_kernel<<<BATCH, 64, 0, stream>>>(
        wns, wds, mu, sigma, w, erev, gleak, vleak, cm,
        output_w, output_b, mean_us, std_us, (float*)d_out);
}

// Round 3
// 592.763 us; speedup vs baseline: 1.1781x; 1.1781x over previous
//
#include <hip/hip_runtime.h>

#define T_LEN 512
#define BATCH 64
#define LOG2E 1.4426950408889634f

typedef float v2f __attribute__((ext_vector_type(2)));

#if defined(__has_builtin)
#  if __has_builtin(__builtin_amdgcn_exp2f)
#    define EXP2F(x) __builtin_amdgcn_exp2f(x)
#  endif
#endif
#ifndef EXP2F
#  define EXP2F(x) __expf((x) * 0.6931471805599453f)
#endif

__device__ __forceinline__ float fast_sigmoid(float x) {
    return __builtin_amdgcn_rcpf(1.0f + __expf(-x));
}

// ---------------------------------------------------------------------------
// Kernel A: per-(b,t) precompute of sensory currents, interleaved
// output layout: [B*T, 32, 2] = (w_num, w_den) pairs per unit
// ---------------------------------------------------------------------------
__global__ __launch_bounds__(256, 1) void sensory_precompute_kernel(
    const float* __restrict__ x,        // [B,T,6]
    const float* __restrict__ mean_us,  // [6]
    const float* __restrict__ std_us,   // [6]
    const float* __restrict__ pre_w1,   // [6,32]
    const float* __restrict__ pre_b1,   // [32]
    const float* __restrict__ pre_w2,   // [32,16]
    const float* __restrict__ pre_b2,   // [16]
    const float* __restrict__ input_w,  // [16]
    const float* __restrict__ input_b,  // [16]
    const float* __restrict__ s_mu,     // [16,32]
    const float* __restrict__ s_sigma,  // [16,32]
    const float* __restrict__ s_w,      // [16,32]
    const float* __restrict__ s_erev,   // [16,32]
    float* __restrict__ wnd_out,        // [B*T, 64] interleaved
    int total)
{
    const int idx = blockIdx.x * blockDim.x + threadIdx.x;
    if (idx >= total) return;

    const float* xp = x + (size_t)idx * 6;
    float xn[6];
    #pragma unroll
    for (int d = 0; d < 6; ++d)
        xn[d] = (xp[d] - mean_us[d]) / std_us[d];

    // 6 -> 32 + GELU (tanh approx, matches jax.nn.gelu default)
    float f1[32];
    #pragma unroll
    for (int h = 0; h < 32; ++h) {
        float a = pre_b1[h];
        #pragma unroll
        for (int d = 0; d < 6; ++d)
            a = fmaf(xn[d], pre_w1[d * 32 + h], a);
        const float y2 = 1.5957691216057308f * fmaf(0.044715f * a * a, a, a);
        f1[h] = a * fast_sigmoid(y2);
    }

    float wn[32], wd[32];
    #pragma unroll
    for (int u = 0; u < 32; ++u) { wn[u] = 0.0f; wd[u] = 0.0f; }

    for (int s = 0; s < 16; ++s) {
        float a = pre_b2[s];
        #pragma unroll
        for (int h = 0; h < 32; ++h)
            a = fmaf(f1[h], pre_w2[h * 16 + s], a);
        const float fs = fmaf(a, input_w[s], input_b[s]);
        #pragma unroll
        for (int u = 0; u < 32; ++u) {
            const int o = s * 32 + u;
            const float sact =
                s_w[o] * fast_sigmoid(s_sigma[o] * (fs - s_mu[o]));
            wn[u] = fmaf(sact, s_erev[o], wn[u]);
            wd[u] += sact;
        }
    }

    float* wo = wnd_out + (size_t)idx * 64;
    #pragma unroll
    for (int u = 0; u < 32; ++u) {
        wo[u * 2]     = wn[u];
        wo[u * 2 + 1] = wd[u];
    }
}

// ---------------------------------------------------------------------------
// Kernel B: sequential LTC scan. One wave per batch element.
// lane l: post-unit u = l&31, pre-half = l>>5 (16 pre units each).
// v broadcast via LDS (1 ds_write + 4 ds_read_b128 per unfold);
// sigmoid arg folded to one pk-fma feeding v_exp (2^x) directly.
// ---------------------------------------------------------------------------
__global__ __launch_bounds__(64, 1) void ltc_scan_kernel(
    const float* __restrict__ wnd_all,  // [B*T, 64] interleaved (wn,wd)
    const float* __restrict__ mu,       // [32,32]  (pre, post)
    const float* __restrict__ sigma,    // [32,32]
    const float* __restrict__ w,        // [32,32]
    const float* __restrict__ erev,     // [32,32]
    const float* __restrict__ gleak,    // [32]
    const float* __restrict__ vleak,    // [32]
    const float* __restrict__ cm,       // [32]
    const float* __restrict__ output_w, // [3]
    const float* __restrict__ output_b, // [3]
    const float* __restrict__ mean_us,  // [6]
    const float* __restrict__ std_us,   // [6]
    float* __restrict__ out)            // [B,T,3]
{
    const int b = blockIdx.x;
    const int lane = threadIdx.x;
    const int u = lane & 31;
    const int pbase = (lane >> 5) << 4;  // 0 or 16

    __shared__ float vbuf[64];

    // per-synapse constants, packed in pairs:
    // exp(-sg*(vp-mu)) = 2^(A*vp + B),  A = -sg*log2e, B = sg*mu*log2e
    v2f A2[8], B2[8], W2[8], WE2[8];
    #pragma unroll
    for (int i = 0; i < 16; ++i) {
        const int o = (pbase + i) * 32 + u;
        const float sg = sigma[o];
        const float ww = w[o];
        A2[i >> 1][i & 1]  = -sg * LOG2E;
        B2[i >> 1][i & 1]  = sg * mu[o] * LOG2E;
        W2[i >> 1][i & 1]  = ww;
        WE2[i >> 1][i & 1] = ww * erev[o];
    }
    const float cmt  = cm[u] * 3.0f;  // cm * ODE_UNFOLDS
    const float gl   = gleak[u];
    const float glvl = gl * vleak[u];

    // fused output affine: out = (v*ow+ob)*std + mean = v*osc + osh
    float osc = 0.0f, osh = 0.0f;
    if (lane < 3) {
        const float sd = std_us[lane];
        osc = output_w[lane] * sd;
        osh = fmaf(output_b[lane], sd, mean_us[lane]);
    }

    const float* wnd_b = wnd_all + (size_t)b * T_LEN * 64 + u * 2;
    float* out_b = out + ((size_t)b * T_LEN) * 3;

    float v = 0.0f;
    vbuf[lane] = 0.0f;
    float2 wnd = *(const float2*)wnd_b;

    for (int t = 0; t < T_LEN; ++t) {
        float2 wnd_n = make_float2(0.0f, 0.0f);
        if (t + 1 < T_LEN)
            wnd_n = *(const float2*)(wnd_b + (size_t)(t + 1) * 64);

        #pragma unroll
        for (int k = 0; k < 3; ++k) {
            const float4* vb = (const float4*)(vbuf + pbase);
            const float4 q0 = vb[0], q1 = vb[1], q2 = vb[2], q3 = vb[3];
            v2f vp[8];
            vp[0] = (v2f){q0.x, q0.y}; vp[1] = (v2f){q0.z, q0.w};
            vp[2] = (v2f){q1.x, q1.y}; vp[3] = (v2f){q1.z, q1.w};
            vp[4] = (v2f){q2.x, q2.y}; vp[5] = (v2f){q2.z, q2.w};
            vp[6] = (v2f){q3.x, q3.y}; vp[7] = (v2f){q3.z, q3.w};

            v2f wna = (v2f){0.f, 0.f}, wnb = (v2f){0.f, 0.f};
            v2f wda = (v2f){0.f, 0.f}, wdb = (v2f){0.f, 0.f};
            #pragma unroll
            for (int j = 0; j < 8; ++j) {
                const v2f arg = A2[j] * vp[j] + B2[j];   // v_pk_fma_f32
                v2f e;
                e.x = EXP2F(arg.x);
                e.y = EXP2F(arg.y);
                const v2f d = e + 1.0f;                  // v_pk_add_f32
                v2f s;
                s.x = __builtin_amdgcn_rcpf(d.x);
                s.y = __builtin_amdgcn_rcpf(d.y);
                if (j & 1) { wnb = WE2[j] * s + wnb; wdb = W2[j] * s + wdb; }
                else       { wna = WE2[j] * s + wna; wda = W2[j] * s + wda; }
            }
            const v2f wn2 = wna + wnb;
            const v2f wd2 = wda + wdb;
            float wnum = wn2.x + wn2.y;
            float wden = wd2.x + wd2.y;
            wnum += __shfl_xor(wnum, 32, 64);
            wden += __shfl_xor(wden, 32, 64);

            const float num = fmaf(cmt, v, glvl + wnum + wnd.x);
            const float den = cmt + gl + wden + wnd.y + 1e-8f;
            v = num * __builtin_amdgcn_rcpf(den);
            vbuf[lane] = v;   // ds_write; in-order LDS pipe per wave
        }

        if (lane < 3)
            out_b[t * 3 + lane] = fmaf(v, osc, osh);

        wnd = wnd_n;
    }
}

// ---------------------------------------------------------------------------
extern "C" void kernel_launch(void* const* d_in, const int* in_sizes, int n_in,
                              void* d_out, int out_size, void* d_ws, size_t ws_size,
                              hipStream_t stream) {
    const float* x        = (const float*)d_in[0];
    const float* mean_us  = (const float*)d_in[1];
    const float* std_us   = (const float*)d_in[2];
    const float* pre_w1   = (const float*)d_in[3];
    const float* pre_b1   = (const float*)d_in[4];
    const float* pre_w2   = (const float*)d_in[5];
    const float* pre_b2   = (const float*)d_in[6];
    const float* input_w  = (const float*)d_in[7];
    const float* input_b  = (const float*)d_in[8];
    const float* s_mu     = (const float*)d_in[9];
    const float* s_sigma  = (const float*)d_in[10];
    const float* s_w      = (const float*)d_in[11];
    const float* s_erev   = (const float*)d_in[12];
    const float* mu       = (const float*)d_in[13];
    const float* sigma    = (const float*)d_in[14];
    const float* w        = (const float*)d_in[15];
    const float* erev     = (const float*)d_in[16];
    const float* gleak    = (const float*)d_in[17];
    const float* vleak    = (const float*)d_in[18];
    const float* cm       = (const float*)d_in[19];
    const float* output_w = (const float*)d_in[20];
    const float* output_b = (const float*)d_in[21];

    const int total = BATCH * T_LEN;  // 32768

    float* wnd = (float*)d_ws;  // [B*T, 64] interleaved (wn,wd), 8 MB

    sensory_precompute_kernel<<<(total + 255) / 256, 256, 0, stream>>>(
        x, mean_us, std_us, pre_w1, pre_b1, pre_w2, pre_b2,
        input_w, input_b, s_mu, s_sigma, s_w, s_erev,
        wnd, total);

    ltc_scan_kernel<<<BATCH, 64, 0, stream>>>(
        wnd, mu, sigma, w, erev, gleak, vleak, cm,
        output_w, output_b, mean_us, std_us, (float*)d_out);
}

// Round 7
// 533.423 us; speedup vs baseline: 1.3092x; 1.1112x over previous
//
#include <hip/hip_runtime.h>

#define T_LEN 512
#define BATCH 64
#define LOG2E 1.4426950408889634f

typedef float v2f __attribute__((ext_vector_type(2)));
typedef unsigned u2i __attribute__((ext_vector_type(2)));

#ifdef __has_builtin
#  if __has_builtin(__builtin_amdgcn_exp2f)
#    define EXP2F(x) __builtin_amdgcn_exp2f(x)
#  endif
#  if __has_builtin(__builtin_amdgcn_permlane32_swap)
#    define HAVE_PL32 1
#  endif
#  if __has_builtin(__builtin_amdgcn_permlane16_swap)
#    define HAVE_PL16 1
#  endif
#endif
#ifndef EXP2F
#  define EXP2F(x) __expf((x) * 0.6931471805599453f)
#endif

__device__ __forceinline__ float fast_sigmoid(float x) {
    return __builtin_amdgcn_rcpf(1.0f + __expf(-x));
}

// candidate fast cross-half sum (verified at runtime before use)
__device__ __forceinline__ float pl32_sum(float x) {
#ifdef HAVE_PL32
    const unsigned xi = __builtin_bit_cast(unsigned, x);
    const u2i r = __builtin_amdgcn_permlane32_swap(xi, xi, false, false);
    return __builtin_bit_cast(float, r.x) + __builtin_bit_cast(float, r.y);
#else
    return x + __shfl_xor(x, 32, 64);
#endif
}

// DPP lane shuffle within 16-lane rows (compile-time control)
template <int CTRL>
__device__ __forceinline__ float dppf(float x) {
    const int xi = __builtin_bit_cast(int, x);
    const int r = __builtin_amdgcn_update_dpp(xi, xi, CTRL, 0xF, 0xF, true);
    return __builtin_bit_cast(float, r);
}
#define DPP_XOR1  0xB1   // quad_perm(1,0,3,2)
#define DPP_XOR2  0x4E   // quad_perm(2,3,0,1)
#define DPP_XOR3  0x1B   // quad_perm(3,2,1,0)
#define DPP_XOR7  0x141  // row_half_mirror
#define DPP_XOR15 0x140  // row_mirror

// fast broadcast: from per-lane v (unit = lane&31) produce vp[j] =
// v[pbase + ((lane&15)^j)] for j=0..15, pure VALU. Verified at runtime.
__device__ __forceinline__ void fast_vp(float v, int lane, float vp[16]) {
    float vlo, vhi;
#ifdef HAVE_PL16
    {
        const unsigned xi = __builtin_bit_cast(unsigned, v);
        const u2i r = __builtin_amdgcn_permlane16_swap(xi, xi, false, false);
        vlo = __builtin_bit_cast(float, r.x);
        vhi = __builtin_bit_cast(float, r.y);
    }
#else
    vlo = __shfl(v, lane & 15, 64);
    vhi = __shfl(v, 16 + (lane & 15), 64);
#endif
    const float vs = (lane & 32) ? vhi : vlo;
    vp[0]  = vs;
    vp[1]  = dppf<DPP_XOR1>(vs);
    vp[2]  = dppf<DPP_XOR2>(vs);
    vp[3]  = dppf<DPP_XOR3>(vs);
    vp[7]  = dppf<DPP_XOR7>(vp[0]);
    vp[6]  = dppf<DPP_XOR7>(vp[1]);
    vp[5]  = dppf<DPP_XOR7>(vp[2]);
    vp[4]  = dppf<DPP_XOR7>(vp[3]);
    vp[15] = dppf<DPP_XOR15>(vp[0]);
    vp[14] = dppf<DPP_XOR15>(vp[1]);
    vp[13] = dppf<DPP_XOR15>(vp[2]);
    vp[12] = dppf<DPP_XOR15>(vp[3]);
    vp[11] = dppf<DPP_XOR15>(vp[4]);
    vp[10] = dppf<DPP_XOR15>(vp[5]);
    vp[9]  = dppf<DPP_XOR15>(vp[6]);
    vp[8]  = dppf<DPP_XOR15>(vp[7]);
}

// ---------------------------------------------------------------------------
// Kernel A: per-(b,t) precompute of sensory currents, interleaved
// ---------------------------------------------------------------------------
__global__ __launch_bounds__(256, 1) void sensory_precompute_kernel(
    const float* __restrict__ x,        // [B,T,6]
    const float* __restrict__ mean_us,  // [6]
    const float* __restrict__ std_us,   // [6]
    const float* __restrict__ pre_w1,   // [6,32]
    const float* __restrict__ pre_b1,   // [32]
    const float* __restrict__ pre_w2,   // [32,16]
    const float* __restrict__ pre_b2,   // [16]
    const float* __restrict__ input_w,  // [16]
    const float* __restrict__ input_b,  // [16]
    const float* __restrict__ s_mu,     // [16,32]
    const float* __restrict__ s_sigma,  // [16,32]
    const float* __restrict__ s_w,      // [16,32]
    const float* __restrict__ s_erev,   // [16,32]
    float* __restrict__ wnd_out,        // [B*T, 64] interleaved
    int total)
{
    const int idx = blockIdx.x * blockDim.x + threadIdx.x;
    if (idx >= total) return;

    const float* xp = x + (size_t)idx * 6;
    float xn[6];
    #pragma unroll
    for (int d = 0; d < 6; ++d)
        xn[d] = (xp[d] - mean_us[d]) / std_us[d];

    float f1[32];
    #pragma unroll
    for (int h = 0; h < 32; ++h) {
        float a = pre_b1[h];
        #pragma unroll
        for (int d = 0; d < 6; ++d)
            a = fmaf(xn[d], pre_w1[d * 32 + h], a);
        const float y2 = 1.5957691216057308f * fmaf(0.044715f * a * a, a, a);
        f1[h] = a * fast_sigmoid(y2);
    }

    float wn[32], wd[32];
    #pragma unroll
    for (int u = 0; u < 32; ++u) { wn[u] = 0.0f; wd[u] = 0.0f; }

    for (int s = 0; s < 16; ++s) {
        float a = pre_b2[s];
        #pragma unroll
        for (int h = 0; h < 32; ++h)
            a = fmaf(f1[h], pre_w2[h * 16 + s], a);
        const float fs = fmaf(a, input_w[s], input_b[s]);
        #pragma unroll
        for (int u = 0; u < 32; ++u) {
            const int o = s * 32 + u;
            const float sact =
                s_w[o] * fast_sigmoid(s_sigma[o] * (fs - s_mu[o]));
            wn[u] = fmaf(sact, s_erev[o], wn[u]);
            wd[u] += sact;
        }
    }

    float* wo = wnd_out + (size_t)idx * 64;
    #pragma unroll
    for (int u = 0; u < 32; ++u) {
        wo[u * 2]     = wn[u];
        wo[u * 2 + 1] = wd[u];
    }
}

// ---------------------------------------------------------------------------
// Kernel B: exact sequential LTC scan, one wave per batch element.
// Runtime self-check picks the broadcast/reduce implementation:
//   fast: permlane16_swap + DPP XOR tree (all-VALU), permlane32 reduce
//   safe: LDS float4 broadcast + shfl_xor reduce  (== round-3 known-pass)
// Synapse math and accumulation order identical to the known-pass kernel.
// ---------------------------------------------------------------------------
__global__ __launch_bounds__(64, 1) void ltc_scan_kernel(
    const float* __restrict__ wnd_all,  // [B*T, 64] interleaved (wn,wd)
    const float* __restrict__ mu,       // [32,32]  (pre, post)
    const float* __restrict__ sigma,    // [32,32]
    const float* __restrict__ w,        // [32,32]
    const float* __restrict__ erev,     // [32,32]
    const float* __restrict__ gleak,    // [32]
    const float* __restrict__ vleak,    // [32]
    const float* __restrict__ cm,       // [32]
    const float* __restrict__ output_w, // [3]
    const float* __restrict__ output_b, // [3]
    const float* __restrict__ mean_us,  // [6]
    const float* __restrict__ std_us,   // [6]
    float* __restrict__ out)            // [B,T,3]
{
    const int b = blockIdx.x;
    const int lane = threadIdx.x;
    const int u = lane & 31;
    const int lx = lane & 15;
    const int pbase = (lane >> 5) << 4;  // 0 or 16

    __shared__ float vbuf[64];

    // ---------------- runtime verification of fast lane primitives --------
    bool ok = true;
    {
        // broadcast check: v pattern is a function of the UNIT (as in real use)
        const float tv = (float)(u * 8 + 3);
        float tvp[16];
        fast_vp(tv, lane, tvp);
        #pragma unroll
        for (int j = 0; j < 16; ++j)
            ok = ok && (tvp[j] == (float)((pbase + (lx ^ j)) * 8 + 3));
        // cross-half-sum check: lane-unique pattern
        const float tg = (float)(lane * 4 + 7);
        const float ts = pl32_sum(tg);
        ok = ok && (ts == (float)(lane * 4 + 7) + (float)((lane ^ 32) * 4 + 7));
    }
    const bool fast = (__ballot(ok) == 0xFFFFFFFFFFFFFFFFull);

    // constants: slot j holds pre-unit (pbase + (lx^j)) on the fast path,
    // (pbase + j) on the safe path. Pair math is elementwise either way.
    v2f A2[8], B2[8], W2[8], WE2[8];
    #pragma unroll
    for (int j = 0; j < 16; ++j) {
        const int p = pbase + (fast ? (lx ^ j) : j);
        const int o = p * 32 + u;
        const float sg = sigma[o];
        const float ww = w[o];
        A2[j >> 1][j & 1]  = -sg * LOG2E;
        B2[j >> 1][j & 1]  = sg * mu[o] * LOG2E;
        W2[j >> 1][j & 1]  = ww;
        WE2[j >> 1][j & 1] = ww * erev[o];
    }
    const float cmt  = cm[u] * 3.0f;  // cm * ODE_UNFOLDS
    const float gl   = gleak[u];
    const float glvl = gl * vleak[u];

    float osc = 0.0f, osh = 0.0f;
    if (lane < 3) {
        const float sd = std_us[lane];
        osc = output_w[lane] * sd;
        osh = fmaf(output_b[lane], sd, mean_us[lane]);
    }

    const float* wnd_b = wnd_all + (size_t)b * T_LEN * 64 + u * 2;
    float* out_b = out + ((size_t)b * T_LEN) * 3;

    float v = 0.0f;
    vbuf[lane] = 0.0f;
    float2 wnd = *(const float2*)wnd_b;

    if (fast) {
        // ------------------ all-VALU serial loop --------------------------
        for (int t = 0; t < T_LEN; ++t) {
            float2 wnd_n = make_float2(0.0f, 0.0f);
            if (t + 1 < T_LEN)
                wnd_n = *(const float2*)(wnd_b + (size_t)(t + 1) * 64);

            #pragma unroll
            for (int k = 0; k < 3; ++k) {
                float vp[16];
                fast_vp(v, lane, vp);

                v2f wna = (v2f){0.f, 0.f}, wnb = (v2f){0.f, 0.f};
                v2f wda = (v2f){0.f, 0.f}, wdb = (v2f){0.f, 0.f};
                #pragma unroll
                for (int j = 0; j < 8; ++j) {
                    const v2f vv = (v2f){vp[2 * j], vp[2 * j + 1]};
                    const v2f arg = A2[j] * vv + B2[j];
                    v2f e;
                    e.x = EXP2F(arg.x);
                    e.y = EXP2F(arg.y);
                    const v2f d = e + 1.0f;
                    v2f s;
                    s.x = __builtin_amdgcn_rcpf(d.x);
                    s.y = __builtin_amdgcn_rcpf(d.y);
                    if (j & 1) { wnb = WE2[j] * s + wnb; wdb = W2[j] * s + wdb; }
                    else       { wna = WE2[j] * s + wna; wda = W2[j] * s + wda; }
                }
                const v2f wn2 = wna + wnb;
                const v2f wd2 = wda + wdb;
                const float wnum = pl32_sum(wn2.x + wn2.y);
                const float wden = pl32_sum(wd2.x + wd2.y);

                const float num = fmaf(cmt, v, glvl + wnum + wnd.x);
                const float den = cmt + gl + wden + wnd.y + 1e-8f;
                v = num * __builtin_amdgcn_rcpf(den);
            }

            if (lane < 3)
                out_b[t * 3 + lane] = fmaf(v, osc, osh);

            wnd = wnd_n;
        }
    } else {
        // ------------------ known-pass LDS loop (round-3 body) ------------
        for (int t = 0; t < T_LEN; ++t) {
            float2 wnd_n = make_float2(0.0f, 0.0f);
            if (t + 1 < T_LEN)
                wnd_n = *(const float2*)(wnd_b + (size_t)(t + 1) * 64);

            #pragma unroll
            for (int k = 0; k < 3; ++k) {
                const float4* vb = (const float4*)(vbuf + pbase);
                const float4 q0 = vb[0], q1 = vb[1], q2 = vb[2], q3 = vb[3];
                v2f vp[8];
                vp[0] = (v2f){q0.x, q0.y}; vp[1] = (v2f){q0.z, q0.w};
                vp[2] = (v2f){q1.x, q1.y}; vp[3] = (v2f){q1.z, q1.w};
                vp[4] = (v2f){q2.x, q2.y}; vp[5] = (v2f){q2.z, q2.w};
                vp[6] = (v2f){q3.x, q3.y}; vp[7] = (v2f){q3.z, q3.w};

                v2f wna = (v2f){0.f, 0.f}, wnb = (v2f){0.f, 0.f};
                v2f wda = (v2f){0.f, 0.f}, wdb = (v2f){0.f, 0.f};
                #pragma unroll
                for (int j = 0; j < 8; ++j) {
                    const v2f arg = A2[j] * vp[j] + B2[j];
                    v2f e;
                    e.x = EXP2F(arg.x);
                    e.y = EXP2F(arg.y);
                    const v2f d = e + 1.0f;
                    v2f s;
                    s.x = __builtin_amdgcn_rcpf(d.x);
                    s.y = __builtin_amdgcn_rcpf(d.y);
                    if (j & 1) { wnb = WE2[j] * s + wnb; wdb = W2[j] * s + wdb; }
                    else       { wna = WE2[j] * s + wna; wda = W2[j] * s + wda; }
                }
                const v2f wn2 = wna + wnb;
                const v2f wd2 = wda + wdb;
                float wnum = wn2.x + wn2.y;
                float wden = wd2.x + wd2.y;
                wnum += __shfl_xor(wnum, 32, 64);
                wden += __shfl_xor(wden, 32, 64);

                const float num = fmaf(cmt, v, glvl + wnum + wnd.x);
                const float den = cmt + gl + wden + wnd.y + 1e-8f;
                v = num * __builtin_amdgcn_rcpf(den);
                vbuf[lane] = v;
            }

            if (lane < 3)
                out_b[t * 3 + lane] = fmaf(v, osc, osh);

            wnd = wnd_n;
        }
    }
}

// ---------------------------------------------------------------------------
extern "C" void kernel_launch(void* const* d_in, const int* in_sizes, int n_in,
                              void* d_out, int out_size, void* d_ws, size_t ws_size,
                              hipStream_t stream) {
    const float* x        = (const float*)d_in[0];
    const float* mean_us  = (const float*)d_in[1];
    const float* std_us   = (const float*)d_in[2];
    const float* pre_w1   = (const float*)d_in[3];
    const float* pre_b1   = (const float*)d_in[4];
    const float* pre_w2   = (const float*)d_in[5];
    const float* pre_b2   = (const float*)d_in[6];
    const float* input_w  = (const float*)d_in[7];
    const float* input_b  = (const float*)d_in[8];
    const float* s_mu     = (const float*)d_in[9];
    const float* s_sigma  = (const float*)d_in[10];
    const float* s_w      = (const float*)d_in[11];
    const float* s_erev   = (const float*)d_in[12];
    const float* mu       = (const float*)d_in[13];
    const float* sigma    = (const float*)d_in[14];
    const float* w        = (const float*)d_in[15];
    const float* erev     = (const float*)d_in[16];
    const float* gleak    = (const float*)d_in[17];
    const float* vleak    = (const float*)d_in[18];
    const float* cm       = (const float*)d_in[19];
    const float* output_w = (const float*)d_in[20];
    const float* output_b = (const float*)d_in[21];

    const int total = BATCH * T_LEN;  // 32768

    float* wnd = (float*)d_ws;  // [B*T, 64] interleaved (wn,wd), 8 MB

    sensory_precompute_kernel<<<(total + 255) / 256, 256, 0, stream>>>(
        x, mean_us, std_us, pre_w1, pre_b1, pre_w2, pre_b2,
        input_w, input_b, s_mu, s_sigma, s_w, s_erev,
        wnd, total);

    ltc_scan_kernel<<<BATCH, 64, 0, stream>>>(
        wnd, mu, sigma, w, erev, gleak, vleak, cm,
        output_w, output_b, mean_us, std_us, (float*)d_out);
}

// Round 8
// 532.948 us; speedup vs baseline: 1.3103x; 1.0009x over previous
//
#include <hip/hip_runtime.h>

#define T_LEN 512
#define BATCH 64
#define LOG2E 1.4426950408889634f

typedef float v2f __attribute__((ext_vector_type(2)));
typedef unsigned u2i __attribute__((ext_vector_type(2)));

#ifdef __has_builtin
#  if __has_builtin(__builtin_amdgcn_exp2f)
#    define EXP2F(x) __builtin_amdgcn_exp2f(x)
#  endif
#  if __has_builtin(__builtin_amdgcn_permlane32_swap)
#    define HAVE_PL32 1
#  endif
#  if __has_builtin(__builtin_amdgcn_permlane16_swap)
#    define HAVE_PL16 1
#  endif
#endif
#ifndef EXP2F
#  define EXP2F(x) __expf((x) * 0.6931471805599453f)
#endif

__device__ __forceinline__ float fast_sigmoid(float x) {
    return __builtin_amdgcn_rcpf(1.0f + __expf(-x));
}

// candidate fast cross-half sum (verified at runtime before use)
__device__ __forceinline__ float pl32_sum(float x) {
#ifdef HAVE_PL32
    const unsigned xi = __builtin_bit_cast(unsigned, x);
    const u2i r = __builtin_amdgcn_permlane32_swap(xi, xi, false, false);
    return __builtin_bit_cast(float, r.x) + __builtin_bit_cast(float, r.y);
#else
    return x + __shfl_xor(x, 32, 64);
#endif
}

// DPP lane shuffle within 16-lane rows (compile-time control)
template <int CTRL>
__device__ __forceinline__ float dppf(float x) {
    const int xi = __builtin_bit_cast(int, x);
    const int r = __builtin_amdgcn_update_dpp(xi, xi, CTRL, 0xF, 0xF, true);
    return __builtin_bit_cast(float, r);
}
#define DPP_XOR1  0xB1   // quad_perm(1,0,3,2)
#define DPP_XOR2  0x4E   // quad_perm(2,3,0,1)
#define DPP_XOR3  0x1B   // quad_perm(3,2,1,0)
#define DPP_XOR7  0x141  // row_half_mirror
#define DPP_XOR15 0x140  // row_mirror

// fast broadcast: from per-lane v (unit = lane&31) produce vp[j] =
// v[pbase + ((lane&15)^j)] for j=0..15, pure VALU. Verified at runtime.
__device__ __forceinline__ void fast_vp(float v, int lane, float vp[16]) {
    float vlo, vhi;
#ifdef HAVE_PL16
    {
        const unsigned xi = __builtin_bit_cast(unsigned, v);
        const u2i r = __builtin_amdgcn_permlane16_swap(xi, xi, false, false);
        vlo = __builtin_bit_cast(float, r.x);
        vhi = __builtin_bit_cast(float, r.y);
    }
#else
    vlo = __shfl(v, lane & 15, 64);
    vhi = __shfl(v, 16 + (lane & 15), 64);
#endif
    const float vs = (lane & 32) ? vhi : vlo;
    vp[0]  = vs;
    vp[1]  = dppf<DPP_XOR1>(vs);
    vp[2]  = dppf<DPP_XOR2>(vs);
    vp[3]  = dppf<DPP_XOR3>(vs);
    vp[7]  = dppf<DPP_XOR7>(vp[0]);
    vp[6]  = dppf<DPP_XOR7>(vp[1]);
    vp[5]  = dppf<DPP_XOR7>(vp[2]);
    vp[4]  = dppf<DPP_XOR7>(vp[3]);
    vp[15] = dppf<DPP_XOR15>(vp[0]);
    vp[14] = dppf<DPP_XOR15>(vp[1]);
    vp[13] = dppf<DPP_XOR15>(vp[2]);
    vp[12] = dppf<DPP_XOR15>(vp[3]);
    vp[11] = dppf<DPP_XOR15>(vp[4]);
    vp[10] = dppf<DPP_XOR15>(vp[5]);
    vp[9]  = dppf<DPP_XOR15>(vp[6]);
    vp[8]  = dppf<DPP_XOR15>(vp[7]);
}

// ---------------------------------------------------------------------------
// Kernel A: per-(b,t) precompute of sensory currents, interleaved
// ---------------------------------------------------------------------------
__global__ __launch_bounds__(256, 1) void sensory_precompute_kernel(
    const float* __restrict__ x,        // [B,T,6]
    const float* __restrict__ mean_us,  // [6]
    const float* __restrict__ std_us,   // [6]
    const float* __restrict__ pre_w1,   // [6,32]
    const float* __restrict__ pre_b1,   // [32]
    const float* __restrict__ pre_w2,   // [32,16]
    const float* __restrict__ pre_b2,   // [16]
    const float* __restrict__ input_w,  // [16]
    const float* __restrict__ input_b,  // [16]
    const float* __restrict__ s_mu,     // [16,32]
    const float* __restrict__ s_sigma,  // [16,32]
    const float* __restrict__ s_w,      // [16,32]
    const float* __restrict__ s_erev,   // [16,32]
    float* __restrict__ wnd_out,        // [B*T, 64] interleaved
    int total)
{
    const int idx = blockIdx.x * blockDim.x + threadIdx.x;
    if (idx >= total) return;

    const float* xp = x + (size_t)idx * 6;
    float xn[6];
    #pragma unroll
    for (int d = 0; d < 6; ++d)
        xn[d] = (xp[d] - mean_us[d]) / std_us[d];

    float f1[32];
    #pragma unroll
    for (int h = 0; h < 32; ++h) {
        float a = pre_b1[h];
        #pragma unroll
        for (int d = 0; d < 6; ++d)
            a = fmaf(xn[d], pre_w1[d * 32 + h], a);
        const float y2 = 1.5957691216057308f * fmaf(0.044715f * a * a, a, a);
        f1[h] = a * fast_sigmoid(y2);
    }

    float wn[32], wd[32];
    #pragma unroll
    for (int u = 0; u < 32; ++u) { wn[u] = 0.0f; wd[u] = 0.0f; }

    for (int s = 0; s < 16; ++s) {
        float a = pre_b2[s];
        #pragma unroll
        for (int h = 0; h < 32; ++h)
            a = fmaf(f1[h], pre_w2[h * 16 + s], a);
        const float fs = fmaf(a, input_w[s], input_b[s]);
        #pragma unroll
        for (int u = 0; u < 32; ++u) {
            const int o = s * 32 + u;
            const float sact =
                s_w[o] * fast_sigmoid(s_sigma[o] * (fs - s_mu[o]));
            wn[u] = fmaf(sact, s_erev[o], wn[u]);
            wd[u] += sact;
        }
    }

    float* wo = wnd_out + (size_t)idx * 64;
    #pragma unroll
    for (int u = 0; u < 32; ++u) {
        wo[u * 2]     = wn[u];
        wo[u * 2 + 1] = wd[u];
    }
}

// ---------------------------------------------------------------------------
// Kernel B: exact sequential LTC scan, one wave per batch element.
// Runtime self-check picks the broadcast/reduce implementation:
//   fast: permlane16_swap + DPP XOR tree (all-VALU), permlane32 reduce,
//         batched reciprocal: 2 rcp per unfold instead of 16
//         (r = rcp(prod d_i); 1/d_i recovered via prefix/suffix products)
//   safe: LDS float4 broadcast + shfl_xor reduce (== round-3 known-pass)
// ---------------------------------------------------------------------------
__global__ __launch_bounds__(64, 1) void ltc_scan_kernel(
    const float* __restrict__ wnd_all,  // [B*T, 64] interleaved (wn,wd)
    const float* __restrict__ mu,       // [32,32]  (pre, post)
    const float* __restrict__ sigma,    // [32,32]
    const float* __restrict__ w,        // [32,32]
    const float* __restrict__ erev,     // [32,32]
    const float* __restrict__ gleak,    // [32]
    const float* __restrict__ vleak,    // [32]
    const float* __restrict__ cm,       // [32]
    const float* __restrict__ output_w, // [3]
    const float* __restrict__ output_b, // [3]
    const float* __restrict__ mean_us,  // [6]
    const float* __restrict__ std_us,   // [6]
    float* __restrict__ out)            // [B,T,3]
{
    const int b = blockIdx.x;
    const int lane = threadIdx.x;
    const int u = lane & 31;
    const int lx = lane & 15;
    const int pbase = (lane >> 5) << 4;  // 0 or 16

    __shared__ float vbuf[64];

    // ---------------- runtime verification of fast lane primitives --------
    bool ok = true;
    {
        const float tv = (float)(u * 8 + 3);
        float tvp[16];
        fast_vp(tv, lane, tvp);
        #pragma unroll
        for (int j = 0; j < 16; ++j)
            ok = ok && (tvp[j] == (float)((pbase + (lx ^ j)) * 8 + 3));
        const float tg = (float)(lane * 4 + 7);
        const float ts = pl32_sum(tg);
        ok = ok && (ts == (float)(lane * 4 + 7) + (float)((lane ^ 32) * 4 + 7));
    }
    const bool fast = (__ballot(ok) == 0xFFFFFFFFFFFFFFFFull);

    // constants: slot j holds pre-unit (pbase + (lx^j)) on the fast path,
    // (pbase + j) on the safe path.
    v2f A2[8], B2[8], W2[8], WE2[8];
    #pragma unroll
    for (int j = 0; j < 16; ++j) {
        const int p = pbase + (fast ? (lx ^ j) : j);
        const int o = p * 32 + u;
        const float sg = sigma[o];
        const float ww = w[o];
        A2[j >> 1][j & 1]  = -sg * LOG2E;
        B2[j >> 1][j & 1]  = sg * mu[o] * LOG2E;
        W2[j >> 1][j & 1]  = ww;
        WE2[j >> 1][j & 1] = ww * erev[o];
    }
    const float cmt  = cm[u] * 3.0f;  // cm * ODE_UNFOLDS
    const float gl   = gleak[u];
    const float glvl = gl * vleak[u];

    float osc = 0.0f, osh = 0.0f;
    if (lane < 3) {
        const float sd = std_us[lane];
        osc = output_w[lane] * sd;
        osh = fmaf(output_b[lane], sd, mean_us[lane]);
    }

    const float* wnd_b = wnd_all + (size_t)b * T_LEN * 64 + u * 2;
    float* out_b = out + ((size_t)b * T_LEN) * 3;

    float v = 0.0f;
    vbuf[lane] = 0.0f;
    float2 wnd = *(const float2*)wnd_b;

    if (fast) {
        // ------------------ all-VALU serial loop, batched rcp -------------
        for (int t = 0; t < T_LEN; ++t) {
            float2 wnd_n = make_float2(0.0f, 0.0f);
            if (t + 1 < T_LEN)
                wnd_n = *(const float2*)(wnd_b + (size_t)(t + 1) * 64);

            // per-timestep invariants of the unfold iteration
            const float bnum = glvl + wnd.x;
            const float bden = cmt + gl + wnd.y + 1e-8f;

            #pragma unroll
            for (int k = 0; k < 3; ++k) {
                float vp[16];
                fast_vp(v, lane, vp);

                // denominators d = 1 + 2^(A*vp+B)
                v2f dv[8];
                #pragma unroll
                for (int j = 0; j < 8; ++j) {
                    const v2f vv = (v2f){vp[2 * j], vp[2 * j + 1]};
                    const v2f arg = A2[j] * vv + B2[j];
                    v2f e;
                    e.x = EXP2F(arg.x);
                    e.y = EXP2F(arg.y);
                    dv[j] = e + 1.0f;
                }

                // batched reciprocals: 2 rcp for all 16 denominators
                float P2[8];
                #pragma unroll
                for (int j = 0; j < 8; ++j)
                    P2[j] = dv[j].x * dv[j].y;
                float P4[4];
                #pragma unroll
                for (int q = 0; q < 4; ++q)
                    P4[q] = P2[2 * q] * P2[2 * q + 1];
                const float P8a = P4[0] * P4[1];
                const float P8b = P4[2] * P4[3];
                const float r8a = __builtin_amdgcn_rcpf(P8a);
                const float r8b = __builtin_amdgcn_rcpf(P8b);
                float t4[4];
                t4[0] = P4[1] * r8a;  t4[1] = P4[0] * r8a;
                t4[2] = P4[3] * r8b;  t4[3] = P4[2] * r8b;
                float t2[8];
                #pragma unroll
                for (int q = 0; q < 4; ++q) {
                    t2[2 * q]     = P2[2 * q + 1] * t4[q];
                    t2[2 * q + 1] = P2[2 * q]     * t4[q];
                }

                // s_j = (1/d_j) = dswap_j * t2_j ; accumulate
                v2f wna = (v2f){0.f, 0.f}, wnb = (v2f){0.f, 0.f};
                v2f wda = (v2f){0.f, 0.f}, wdb = (v2f){0.f, 0.f};
                #pragma unroll
                for (int j = 0; j < 8; ++j) {
                    const v2f s =
                        (v2f){dv[j].y, dv[j].x} * (v2f){t2[j], t2[j]};
                    if (j & 1) { wnb = WE2[j] * s + wnb; wdb = W2[j] * s + wdb; }
                    else       { wna = WE2[j] * s + wna; wda = W2[j] * s + wda; }
                }
                const v2f wn2 = wna + wnb;
                const v2f wd2 = wda + wdb;
                const float wnum = pl32_sum(wn2.x + wn2.y);
                const float wden = pl32_sum(wd2.x + wd2.y);

                const float num = fmaf(cmt, v, bnum + wnum);
                v = num * __builtin_amdgcn_rcpf(bden + wden);
            }

            if (lane < 3)
                out_b[t * 3 + lane] = fmaf(v, osc, osh);

            wnd = wnd_n;
        }
    } else {
        // ------------------ known-pass LDS loop (round-3 body) ------------
        for (int t = 0; t < T_LEN; ++t) {
            float2 wnd_n = make_float2(0.0f, 0.0f);
            if (t + 1 < T_LEN)
                wnd_n = *(const float2*)(wnd_b + (size_t)(t + 1) * 64);

            #pragma unroll
            for (int k = 0; k < 3; ++k) {
                const float4* vb = (const float4*)(vbuf + pbase);
                const float4 q0 = vb[0], q1 = vb[1], q2 = vb[2], q3 = vb[3];
                v2f vp[8];
                vp[0] = (v2f){q0.x, q0.y}; vp[1] = (v2f){q0.z, q0.w};
                vp[2] = (v2f){q1.x, q1.y}; vp[3] = (v2f){q1.z, q1.w};
                vp[4] = (v2f){q2.x, q2.y}; vp[5] = (v2f){q2.z, q2.w};
                vp[6] = (v2f){q3.x, q3.y}; vp[7] = (v2f){q3.z, q3.w};

                v2f wna = (v2f){0.f, 0.f}, wnb = (v2f){0.f, 0.f};
                v2f wda = (v2f){0.f, 0.f}, wdb = (v2f){0.f, 0.f};
                #pragma unroll
                for (int j = 0; j < 8; ++j) {
                    const v2f arg = A2[j] * vp[j] + B2[j];
                    v2f e;
                    e.x = EXP2F(arg.x);
                    e.y = EXP2F(arg.y);
                    const v2f d = e + 1.0f;
                    v2f s;
                    s.x = __builtin_amdgcn_rcpf(d.x);
                    s.y = __builtin_amdgcn_rcpf(d.y);
                    if (j & 1) { wnb = WE2[j] * s + wnb; wdb = W2[j] * s + wdb; }
                    else       { wna = WE2[j] * s + wna; wda = W2[j] * s + wda; }
                }
                const v2f wn2 = wna + wnb;
                const v2f wd2 = wda + wdb;
                float wnum = wn2.x + wn2.y;
                float wden = wd2.x + wd2.y;
                wnum += __shfl_xor(wnum, 32, 64);
                wden += __shfl_xor(wden, 32, 64);

                const float num = fmaf(cmt, v, glvl + wnum + wnd.x);
                const float den = cmt + gl + wden + wnd.y + 1e-8f;
                v = num * __builtin_amdgcn_rcpf(den);
                vbuf[lane] = v;
            }

            if (lane < 3)
                out_b[t * 3 + lane] = fmaf(v, osc, osh);

            wnd = wnd_n;
        }
    }
}

// ---------------------------------------------------------------------------
extern "C" void kernel_launch(void* const* d_in, const int* in_sizes, int n_in,
                              void* d_out, int out_size, void* d_ws, size_t ws_size,
                              hipStream_t stream) {
    const float* x        = (const float*)d_in[0];
    const float* mean_us  = (const float*)d_in[1];
    const float* std_us   = (const float*)d_in[2];
    const float* pre_w1   = (const float*)d_in[3];
    const float* pre_b1   = (const float*)d_in[4];
    const float* pre_w2   = (const float*)d_in[5];
    const float* pre_b2   = (const float*)d_in[6];
    const float* input_w  = (const float*)d_in[7];
    const float* input_b  = (const float*)d_in[8];
    const float* s_mu     = (const float*)d_in[9];
    const float* s_sigma  = (const float*)d_in[10];
    const float* s_w      = (const float*)d_in[11];
    const float* s_erev   = (const float*)d_in[12];
    const float* mu       = (const float*)d_in[13];
    const float* sigma    = (const float*)d_in[14];
    const float* w        = (const float*)d_in[15];
    const float* erev     = (const float*)d_in[16];
    const float* gleak    = (const float*)d_in[17];
    const float* vleak    = (const float*)d_in[18];
    const float* cm       = (const float*)d_in[19];
    const float* output_w = (const float*)d_in[20];
    const float* output_b = (const float*)d_in[21];

    const int total = BATCH * T_LEN;  // 32768

    float* wnd = (float*)d_ws;  // [B*T, 64] interleaved (wn,wd), 8 MB

    sensory_precompute_kernel<<<(total + 255) / 256, 256, 0, stream>>>(
        x, mean_us, std_us, pre_w1, pre_b1, pre_w2, pre_b2,
        input_w, input_b, s_mu, s_sigma, s_w, s_erev,
        wnd, total);

    ltc_scan_kernel<<<BATCH, 64, 0, stream>>>(
        wnd, mu, sigma, w, erev, gleak, vleak, cm,
        output_w, output_b, mean_us, std_us, (float*)d_out);
}

// Round 9
// 527.644 us; speedup vs baseline: 1.3235x; 1.0101x over previous
//
#include <hip/hip_runtime.h>

#define T_LEN 512
#define BATCH 64
#define LOG2E 1.4426950408889634f

typedef float v2f __attribute__((ext_vector_type(2)));
typedef unsigned u2i __attribute__((ext_vector_type(2)));

#ifdef __has_builtin
#  if __has_builtin(__builtin_amdgcn_exp2f)
#    define EXP2F(x) __builtin_amdgcn_exp2f(x)
#  endif
#  if __has_builtin(__builtin_amdgcn_permlane32_swap)
#    define HAVE_PL32 1
#  endif
#  if __has_builtin(__builtin_amdgcn_permlane16_swap)
#    define HAVE_PL16 1
#  endif
#endif
#ifndef EXP2F
#  define EXP2F(x) __expf((x) * 0.6931471805599453f)
#endif

__device__ __forceinline__ float fast_sigmoid(float x) {
    return __builtin_amdgcn_rcpf(1.0f + __expf(-x));
}

// candidate fast cross-half sum (verified at runtime before use)
__device__ __forceinline__ float pl32_sum(float x) {
#ifdef HAVE_PL32
    const unsigned xi = __builtin_bit_cast(unsigned, x);
    const u2i r = __builtin_amdgcn_permlane32_swap(xi, xi, false, false);
    return __builtin_bit_cast(float, r.x) + __builtin_bit_cast(float, r.y);
#else
    return x + __shfl_xor(x, 32, 64);
#endif
}

// DPP lane shuffle within 16-lane rows (compile-time control)
template <int CTRL>
__device__ __forceinline__ float dppf(float x) {
    const int xi = __builtin_bit_cast(int, x);
    const int r = __builtin_amdgcn_update_dpp(xi, xi, CTRL, 0xF, 0xF, true);
    return __builtin_bit_cast(float, r);
}
#define DPP_XOR1  0xB1   // quad_perm(1,0,3,2)
#define DPP_XOR2  0x4E   // quad_perm(2,3,0,1)
#define DPP_XOR3  0x1B   // quad_perm(3,2,1,0)
#define DPP_XOR7  0x141  // row_half_mirror
#define DPP_XOR15 0x140  // row_mirror

// fast broadcast: from per-lane v (unit = lane&31) produce vp[j] =
// v[pbase + ((lane&15)^j)] for j=0..15, pure VALU. Verified at runtime.
__device__ __forceinline__ void fast_vp(float v, int lane, float vp[16]) {
    float vlo, vhi;
#ifdef HAVE_PL16
    {
        const unsigned xi = __builtin_bit_cast(unsigned, v);
        const u2i r = __builtin_amdgcn_permlane16_swap(xi, xi, false, false);
        vlo = __builtin_bit_cast(float, r.x);
        vhi = __builtin_bit_cast(float, r.y);
    }
#else
    vlo = __shfl(v, lane & 15, 64);
    vhi = __shfl(v, 16 + (lane & 15), 64);
#endif
    const float vs = (lane & 32) ? vhi : vlo;
    vp[0]  = vs;
    vp[1]  = dppf<DPP_XOR1>(vs);
    vp[2]  = dppf<DPP_XOR2>(vs);
    vp[3]  = dppf<DPP_XOR3>(vs);
    vp[7]  = dppf<DPP_XOR7>(vp[0]);
    vp[6]  = dppf<DPP_XOR7>(vp[1]);
    vp[5]  = dppf<DPP_XOR7>(vp[2]);
    vp[4]  = dppf<DPP_XOR7>(vp[3]);
    vp[15] = dppf<DPP_XOR15>(vp[0]);
    vp[14] = dppf<DPP_XOR15>(vp[1]);
    vp[13] = dppf<DPP_XOR15>(vp[2]);
    vp[12] = dppf<DPP_XOR15>(vp[3]);
    vp[11] = dppf<DPP_XOR15>(vp[4]);
    vp[10] = dppf<DPP_XOR15>(vp[5]);
    vp[9]  = dppf<DPP_XOR15>(vp[6]);
    vp[8]  = dppf<DPP_XOR15>(vp[7]);
}

// ---------------------------------------------------------------------------
// Kernel A: per-(b,t) precompute of sensory currents, interleaved
// ---------------------------------------------------------------------------
__global__ __launch_bounds__(256, 1) void sensory_precompute_kernel(
    const float* __restrict__ x,        // [B,T,6]
    const float* __restrict__ mean_us,  // [6]
    const float* __restrict__ std_us,   // [6]
    const float* __restrict__ pre_w1,   // [6,32]
    const float* __restrict__ pre_b1,   // [32]
    const float* __restrict__ pre_w2,   // [32,16]
    const float* __restrict__ pre_b2,   // [16]
    const float* __restrict__ input_w,  // [16]
    const float* __restrict__ input_b,  // [16]
    const float* __restrict__ s_mu,     // [16,32]
    const float* __restrict__ s_sigma,  // [16,32]
    const float* __restrict__ s_w,      // [16,32]
    const float* __restrict__ s_erev,   // [16,32]
    float* __restrict__ wnd_out,        // [B*T, 64] interleaved
    int total)
{
    const int idx = blockIdx.x * blockDim.x + threadIdx.x;
    if (idx >= total) return;

    const float* xp = x + (size_t)idx * 6;
    float xn[6];
    #pragma unroll
    for (int d = 0; d < 6; ++d)
        xn[d] = (xp[d] - mean_us[d]) / std_us[d];

    float f1[32];
    #pragma unroll
    for (int h = 0; h < 32; ++h) {
        float a = pre_b1[h];
        #pragma unroll
        for (int d = 0; d < 6; ++d)
            a = fmaf(xn[d], pre_w1[d * 32 + h], a);
        const float y2 = 1.5957691216057308f * fmaf(0.044715f * a * a, a, a);
        f1[h] = a * fast_sigmoid(y2);
    }

    float wn[32], wd[32];
    #pragma unroll
    for (int u = 0; u < 32; ++u) { wn[u] = 0.0f; wd[u] = 0.0f; }

    for (int s = 0; s < 16; ++s) {
        float a = pre_b2[s];
        #pragma unroll
        for (int h = 0; h < 32; ++h)
            a = fmaf(f1[h], pre_w2[h * 16 + s], a);
        const float fs = fmaf(a, input_w[s], input_b[s]);
        #pragma unroll
        for (int u = 0; u < 32; ++u) {
            const int o = s * 32 + u;
            const float sact =
                s_w[o] * fast_sigmoid(s_sigma[o] * (fs - s_mu[o]));
            wn[u] = fmaf(sact, s_erev[o], wn[u]);
            wd[u] += sact;
        }
    }

    float* wo = wnd_out + (size_t)idx * 64;
    #pragma unroll
    for (int u = 0; u < 32; ++u) {
        wo[u * 2]     = wn[u];
        wo[u * 2 + 1] = wd[u];
    }
}

// ---------------------------------------------------------------------------
// Kernel B: exact sequential LTC scan, one wave per batch element.
// Runtime self-check picks the broadcast/reduce implementation:
//   fast: permlane16_swap + DPP XOR tree (all-VALU), permlane32 reduce,
//         batched reciprocal (2 rcp/unfold), deep 4-timestep register
//         prefetch of the sensory stream (covers ~900 cy HBM latency)
//   safe: LDS float4 broadcast + shfl_xor reduce (== round-3 known-pass)
// ---------------------------------------------------------------------------
__global__ __launch_bounds__(64, 1) void ltc_scan_kernel(
    const float* __restrict__ wnd_all,  // [B*T, 64] interleaved (wn,wd)
    const float* __restrict__ mu,       // [32,32]  (pre, post)
    const float* __restrict__ sigma,    // [32,32]
    const float* __restrict__ w,        // [32,32]
    const float* __restrict__ erev,     // [32,32]
    const float* __restrict__ gleak,    // [32]
    const float* __restrict__ vleak,    // [32]
    const float* __restrict__ cm,       // [32]
    const float* __restrict__ output_w, // [3]
    const float* __restrict__ output_b, // [3]
    const float* __restrict__ mean_us,  // [6]
    const float* __restrict__ std_us,   // [6]
    float* __restrict__ out)            // [B,T,3]
{
    const int b = blockIdx.x;
    const int lane = threadIdx.x;
    const int u = lane & 31;
    const int lx = lane & 15;
    const int pbase = (lane >> 5) << 4;  // 0 or 16

    __shared__ float vbuf[64];

    // ---------------- runtime verification of fast lane primitives --------
    bool ok = true;
    {
        const float tv = (float)(u * 8 + 3);
        float tvp[16];
        fast_vp(tv, lane, tvp);
        #pragma unroll
        for (int j = 0; j < 16; ++j)
            ok = ok && (tvp[j] == (float)((pbase + (lx ^ j)) * 8 + 3));
        const float tg = (float)(lane * 4 + 7);
        const float ts = pl32_sum(tg);
        ok = ok && (ts == (float)(lane * 4 + 7) + (float)((lane ^ 32) * 4 + 7));
    }
    const bool fast = (__ballot(ok) == 0xFFFFFFFFFFFFFFFFull);

    // constants: slot j holds pre-unit (pbase + (lx^j)) on the fast path,
    // (pbase + j) on the safe path.
    v2f A2[8], B2[8], W2[8], WE2[8];
    #pragma unroll
    for (int j = 0; j < 16; ++j) {
        const int p = pbase + (fast ? (lx ^ j) : j);
        const int o = p * 32 + u;
        const float sg = sigma[o];
        const float ww = w[o];
        A2[j >> 1][j & 1]  = -sg * LOG2E;
        B2[j >> 1][j & 1]  = sg * mu[o] * LOG2E;
        W2[j >> 1][j & 1]  = ww;
        WE2[j >> 1][j & 1] = ww * erev[o];
    }
    const float cmt  = cm[u] * 3.0f;  // cm * ODE_UNFOLDS
    const float gl   = gleak[u];
    const float glvl = gl * vleak[u];

    float osc = 0.0f, osh = 0.0f;
    if (lane < 3) {
        const float sd = std_us[lane];
        osc = output_w[lane] * sd;
        osh = fmaf(output_b[lane], sd, mean_us[lane]);
    }

    const float* wnd_b = wnd_all + (size_t)b * T_LEN * 64 + u * 2;
    float* out_b = out + ((size_t)b * T_LEN) * 3;

#define LDW(tt) (*(const float2*)(wnd_b + (size_t)(tt) * 64))

    float v = 0.0f;
    vbuf[lane] = 0.0f;

    if (fast) {
        // ---------- all-VALU serial loop, deep register prefetch ----------
        // one timestep (3 unfolds) on the current v, using sensory pair wt
        auto do_t = [&](const float2 wt, const int t) {
            const float bnum = glvl + wt.x;
            const float bden = cmt + gl + wt.y + 1e-8f;
            #pragma unroll
            for (int k = 0; k < 3; ++k) {
                float vp[16];
                fast_vp(v, lane, vp);

                // denominators d = 1 + 2^(A*vp+B)
                v2f dv[8];
                #pragma unroll
                for (int j = 0; j < 8; ++j) {
                    const v2f vv = (v2f){vp[2 * j], vp[2 * j + 1]};
                    const v2f arg = A2[j] * vv + B2[j];
                    v2f e;
                    e.x = EXP2F(arg.x);
                    e.y = EXP2F(arg.y);
                    dv[j] = e + 1.0f;
                }

                // batched reciprocals: 2 rcp for all 16 denominators
                float P2[8];
                #pragma unroll
                for (int j = 0; j < 8; ++j)
                    P2[j] = dv[j].x * dv[j].y;
                float P4[4];
                #pragma unroll
                for (int q = 0; q < 4; ++q)
                    P4[q] = P2[2 * q] * P2[2 * q + 1];
                const float P8a = P4[0] * P4[1];
                const float P8b = P4[2] * P4[3];
                const float r8a = __builtin_amdgcn_rcpf(P8a);
                const float r8b = __builtin_amdgcn_rcpf(P8b);
                float t4[4];
                t4[0] = P4[1] * r8a;  t4[1] = P4[0] * r8a;
                t4[2] = P4[3] * r8b;  t4[3] = P4[2] * r8b;
                float t2[8];
                #pragma unroll
                for (int q = 0; q < 4; ++q) {
                    t2[2 * q]     = P2[2 * q + 1] * t4[q];
                    t2[2 * q + 1] = P2[2 * q]     * t4[q];
                }

                v2f wna = (v2f){0.f, 0.f}, wnb = (v2f){0.f, 0.f};
                v2f wda = (v2f){0.f, 0.f}, wdb = (v2f){0.f, 0.f};
                #pragma unroll
                for (int j = 0; j < 8; ++j) {
                    const v2f s =
                        (v2f){dv[j].y, dv[j].x} * (v2f){t2[j], t2[j]};
                    if (j & 1) { wnb = WE2[j] * s + wnb; wdb = W2[j] * s + wdb; }
                    else       { wna = WE2[j] * s + wna; wda = W2[j] * s + wda; }
                }
                const v2f wn2 = wna + wnb;
                const v2f wd2 = wda + wdb;
                const float wnum = pl32_sum(wn2.x + wn2.y);
                const float wden = pl32_sum(wd2.x + wd2.y);

                const float num = fmaf(cmt, v, bnum + wnum);
                v = num * __builtin_amdgcn_rcpf(bden + wden);
            }
            if (lane < 3)
                out_b[t * 3 + lane] = fmaf(v, osc, osh);
        };

        // rotating 4-deep prefetch queue (distance 4 timesteps ≈ 3200 cy)
        float2 w0 = LDW(0), w1 = LDW(1), w2 = LDW(2), w3 = LDW(3);
        for (int t = 0; t < T_LEN; t += 2) {
            const int ta = (t + 4 < T_LEN) ? t + 4 : T_LEN - 1;
            const int tb = (t + 5 < T_LEN) ? t + 5 : T_LEN - 1;
            const float2 n0 = LDW(ta);
            const float2 n1 = LDW(tb);

            do_t(w0, t);
            do_t(w1, t + 1);

            w0 = w2; w1 = w3; w2 = n0; w3 = n1;
        }
    } else {
        // ------------------ known-pass LDS loop (round-3 body) ------------
        float2 wnd = LDW(0);
        for (int t = 0; t < T_LEN; ++t) {
            float2 wnd_n = make_float2(0.0f, 0.0f);
            if (t + 1 < T_LEN)
                wnd_n = LDW(t + 1);

            #pragma unroll
            for (int k = 0; k < 3; ++k) {
                const float4* vb = (const float4*)(vbuf + pbase);
                const float4 q0 = vb[0], q1 = vb[1], q2 = vb[2], q3 = vb[3];
                v2f vp[8];
                vp[0] = (v2f){q0.x, q0.y}; vp[1] = (v2f){q0.z, q0.w};
                vp[2] = (v2f){q1.x, q1.y}; vp[3] = (v2f){q1.z, q1.w};
                vp[4] = (v2f){q2.x, q2.y}; vp[5] = (v2f){q2.z, q2.w};
                vp[6] = (v2f){q3.x, q3.y}; vp[7] = (v2f){q3.z, q3.w};

                v2f wna = (v2f){0.f, 0.f}, wnb = (v2f){0.f, 0.f};
                v2f wda = (v2f){0.f, 0.f}, wdb = (v2f){0.f, 0.f};
                #pragma unroll
                for (int j = 0; j < 8; ++j) {
                    const v2f arg = A2[j] * vp[j] + B2[j];
                    v2f e;
                    e.x = EXP2F(arg.x);
                    e.y = EXP2F(arg.y);
                    const v2f d = e + 1.0f;
                    v2f s;
                    s.x = __builtin_amdgcn_rcpf(d.x);
                    s.y = __builtin_amdgcn_rcpf(d.y);
                    if (j & 1) { wnb = WE2[j] * s + wnb; wdb = W2[j] * s + wdb; }
                    else       { wna = WE2[j] * s + wna; wda = W2[j] * s + wda; }
                }
                const v2f wn2 = wna + wnb;
                const v2f wd2 = wda + wdb;
                float wnum = wn2.x + wn2.y;
                float wden = wd2.x + wd2.y;
                wnum += __shfl_xor(wnum, 32, 64);
                wden += __shfl_xor(wden, 32, 64);

                const float num = fmaf(cmt, v, glvl + wnum + wnd.x);
                const float den = cmt + gl + wden + wnd.y + 1e-8f;
                v = num * __builtin_amdgcn_rcpf(den);
                vbuf[lane] = v;
            }

            if (lane < 3)
                out_b[t * 3 + lane] = fmaf(v, osc, osh);

            wnd = wnd_n;
        }
    }
#undef LDW
}

// ---------------------------------------------------------------------------
extern "C" void kernel_launch(void* const* d_in, const int* in_sizes, int n_in,
                              void* d_out, int out_size, void* d_ws, size_t ws_size,
                              hipStream_t stream) {
    const float* x        = (const float*)d_in[0];
    const float* mean_us  = (const float*)d_in[1];
    const float* std_us   = (const float*)d_in[2];
    const float* pre_w1   = (const float*)d_in[3];
    const float* pre_b1   = (const float*)d_in[4];
    const float* pre_w2   = (const float*)d_in[5];
    const float* pre_b2   = (const float*)d_in[6];
    const float* input_w  = (const float*)d_in[7];
    const float* input_b  = (const float*)d_in[8];
    const float* s_mu     = (const float*)d_in[9];
    const float* s_sigma  = (const float*)d_in[10];
    const float* s_w      = (const float*)d_in[11];
    const float* s_erev   = (const float*)d_in[12];
    const float* mu       = (const float*)d_in[13];
    const float* sigma    = (const float*)d_in[14];
    const float* w        = (const float*)d_in[15];
    const float* erev     = (const float*)d_in[16];
    const float* gleak    = (const float*)d_in[17];
    const float* vleak    = (const float*)d_in[18];
    const float* cm       = (const float*)d_in[19];
    const float* output_w = (const float*)d_in[20];
    const float* output_b = (const float*)d_in[21];

    const int total = BATCH * T_LEN;  // 32768

    float* wnd = (float*)d_ws;  // [B*T, 64] interleaved (wn,wd), 8 MB

    sensory_precompute_kernel<<<(total + 255) / 256, 256, 0, stream>>>(
        x, mean_us, std_us, pre_w1, pre_b1, pre_w2, pre_b2,
        input_w, input_b, s_mu, s_sigma, s_w, s_erev,
        wnd, total);

    ltc_scan_kernel<<<BATCH, 64, 0, stream>>>(
        wnd, mu, sigma, w, erev, gleak, vleak, cm,
        output_w, output_b, mean_us, std_us, (float*)d_out);
}

// Round 12
// 526.572 us; speedup vs baseline: 1.3262x; 1.0020x over previous
//
#include <hip/hip_runtime.h>

#define T_LEN 512
#define BATCH 64
#define LOG2E 1.4426950408889634f

typedef float v2f __attribute__((ext_vector_type(2)));
typedef unsigned u2i __attribute__((ext_vector_type(2)));

#ifdef __has_builtin
#  if __has_builtin(__builtin_amdgcn_exp2f)
#    define EXP2F(x) __builtin_amdgcn_exp2f(x)
#  endif
#  if __has_builtin(__builtin_amdgcn_permlane32_swap)
#    define HAVE_PL32 1
#  endif
#  if __has_builtin(__builtin_amdgcn_permlane16_swap)
#    define HAVE_PL16 1
#  endif
#endif
#ifndef EXP2F
#  define EXP2F(x) __expf((x) * 0.6931471805599453f)
#endif

__device__ __forceinline__ float fast_sigmoid(float x) {
    return __builtin_amdgcn_rcpf(1.0f + __expf(-x));
}

// candidate fast cross-half sum (verified at runtime before use)
__device__ __forceinline__ float pl32_sum(float x) {
#ifdef HAVE_PL32
    const unsigned xi = __builtin_bit_cast(unsigned, x);
    const u2i r = __builtin_amdgcn_permlane32_swap(xi, xi, false, false);
    return __builtin_bit_cast(float, r.x) + __builtin_bit_cast(float, r.y);
#else
    return x + __shfl_xor(x, 32, 64);
#endif
}

// DPP lane shuffle within 16-lane rows (compile-time control)
template <int CTRL>
__device__ __forceinline__ float dppf(float x) {
    const int xi = __builtin_bit_cast(int, x);
    const int r = __builtin_amdgcn_update_dpp(xi, xi, CTRL, 0xF, 0xF, true);
    return __builtin_bit_cast(float, r);
}
#define DPP_XOR1  0xB1   // quad_perm(1,0,3,2)
#define DPP_XOR2  0x4E   // quad_perm(2,3,0,1)
#define DPP_XOR3  0x1B   // quad_perm(3,2,1,0)
#define DPP_XOR7  0x141  // row_half_mirror
#define DPP_XOR15 0x140  // row_mirror

// fast broadcast: from per-lane v (unit = lane&31) produce vp[j] =
// v[pbase + ((lane&15)^j)] for j=0..15, pure VALU. Verified at runtime.
__device__ __forceinline__ void fast_vp(float v, int lane, float vp[16]) {
    float vlo, vhi;
#ifdef HAVE_PL16
    {
        const unsigned xi = __builtin_bit_cast(unsigned, v);
        const u2i r = __builtin_amdgcn_permlane16_swap(xi, xi, false, false);
        vlo = __builtin_bit_cast(float, r.x);
        vhi = __builtin_bit_cast(float, r.y);
    }
#else
    vlo = __shfl(v, lane & 15, 64);
    vhi = __shfl(v, 16 + (lane & 15), 64);
#endif
    const float vs = (lane & 32) ? vhi : vlo;
    vp[0]  = vs;
    vp[1]  = dppf<DPP_XOR1>(vs);
    vp[2]  = dppf<DPP_XOR2>(vs);
    vp[3]  = dppf<DPP_XOR3>(vs);
    vp[7]  = dppf<DPP_XOR7>(vp[0]);
    vp[6]  = dppf<DPP_XOR7>(vp[1]);
    vp[5]  = dppf<DPP_XOR7>(vp[2]);
    vp[4]  = dppf<DPP_XOR7>(vp[3]);
    vp[15] = dppf<DPP_XOR15>(vp[0]);
    vp[14] = dppf<DPP_XOR15>(vp[1]);
    vp[13] = dppf<DPP_XOR15>(vp[2]);
    vp[12] = dppf<DPP_XOR15>(vp[3]);
    vp[11] = dppf<DPP_XOR15>(vp[4]);
    vp[10] = dppf<DPP_XOR15>(vp[5]);
    vp[9]  = dppf<DPP_XOR15>(vp[6]);
    vp[8]  = dppf<DPP_XOR15>(vp[7]);
}

// ---------------------------------------------------------------------------
// Kernel A: per-(b,t) precompute of sensory currents, interleaved
// ---------------------------------------------------------------------------
__global__ __launch_bounds__(256, 1) void sensory_precompute_kernel(
    const float* __restrict__ x,        // [B,T,6]
    const float* __restrict__ mean_us,  // [6]
    const float* __restrict__ std_us,   // [6]
    const float* __restrict__ pre_w1,   // [6,32]
    const float* __restrict__ pre_b1,   // [32]
    const float* __restrict__ pre_w2,   // [32,16]
    const float* __restrict__ pre_b2,   // [16]
    const float* __restrict__ input_w,  // [16]
    const float* __restrict__ input_b,  // [16]
    const float* __restrict__ s_mu,     // [16,32]
    const float* __restrict__ s_sigma,  // [16,32]
    const float* __restrict__ s_w,      // [16,32]
    const float* __restrict__ s_erev,   // [16,32]
    float* __restrict__ wnd_out,        // [B*T, 64] interleaved
    int total)
{
    const int idx = blockIdx.x * blockDim.x + threadIdx.x;
    if (idx >= total) return;

    const float* xp = x + (size_t)idx * 6;
    float xn[6];
    #pragma unroll
    for (int d = 0; d < 6; ++d)
        xn[d] = (xp[d] - mean_us[d]) / std_us[d];

    float f1[32];
    #pragma unroll
    for (int h = 0; h < 32; ++h) {
        float a = pre_b1[h];
        #pragma unroll
        for (int d = 0; d < 6; ++d)
            a = fmaf(xn[d], pre_w1[d * 32 + h], a);
        const float y2 = 1.5957691216057308f * fmaf(0.044715f * a * a, a, a);
        f1[h] = a * fast_sigmoid(y2);
    }

    float wn[32], wd[32];
    #pragma unroll
    for (int u = 0; u < 32; ++u) { wn[u] = 0.0f; wd[u] = 0.0f; }

    for (int s = 0; s < 16; ++s) {
        float a = pre_b2[s];
        #pragma unroll
        for (int h = 0; h < 32; ++h)
            a = fmaf(f1[h], pre_w2[h * 16 + s], a);
        const float fs = fmaf(a, input_w[s], input_b[s]);
        #pragma unroll
        for (int u = 0; u < 32; ++u) {
            const int o = s * 32 + u;
            const float sact =
                s_w[o] * fast_sigmoid(s_sigma[o] * (fs - s_mu[o]));
            wn[u] = fmaf(sact, s_erev[o], wn[u]);
            wd[u] += sact;
        }
    }

    float* wo = wnd_out + (size_t)idx * 64;
    #pragma unroll
    for (int u = 0; u < 32; ++u) {
        wo[u * 2]     = wn[u];
        wo[u * 2 + 1] = wd[u];
    }
}

// ---------------------------------------------------------------------------
// Kernel B: exact sequential LTC scan, one wave per batch element.
// Runtime self-check picks the broadcast/reduce implementation:
//   fast: permlane16_swap + DPP XOR tree (all-VALU), permlane32 reduce,
//         batched reciprocal (2 rcp/unfold), deep 4-timestep register
//         prefetch of the sensory stream (covers ~900 cy HBM latency)
//   safe: LDS float4 broadcast + shfl_xor reduce (== round-3 known-pass)
// ---------------------------------------------------------------------------
__global__ __launch_bounds__(64, 1) void ltc_scan_kernel(
    const float* __restrict__ wnd_all,  // [B*T, 64] interleaved (wn,wd)
    const float* __restrict__ mu,       // [32,32]  (pre, post)
    const float* __restrict__ sigma,    // [32,32]
    const float* __restrict__ w,        // [32,32]
    const float* __restrict__ erev,     // [32,32]
    const float* __restrict__ gleak,    // [32]
    const float* __restrict__ vleak,    // [32]
    const float* __restrict__ cm,       // [32]
    const float* __restrict__ output_w, // [3]
    const float* __restrict__ output_b, // [3]
    const float* __restrict__ mean_us,  // [6]
    const float* __restrict__ std_us,   // [6]
    float* __restrict__ out)            // [B,T,3]
{
    const int b = blockIdx.x;
    const int lane = threadIdx.x;
    const int u = lane & 31;
    const int lx = lane & 15;
    const int pbase = (lane >> 5) << 4;  // 0 or 16

    __shared__ float vbuf[64];

    // ---------------- runtime verification of fast lane primitives --------
    bool ok = true;
    {
        const float tv = (float)(u * 8 + 3);
        float tvp[16];
        fast_vp(tv, lane, tvp);
        #pragma unroll
        for (int j = 0; j < 16; ++j)
            ok = ok && (tvp[j] == (float)((pbase + (lx ^ j)) * 8 + 3));
        const float tg = (float)(lane * 4 + 7);
        const float ts = pl32_sum(tg);
        ok = ok && (ts == (float)(lane * 4 + 7) + (float)((lane ^ 32) * 4 + 7));
    }
    const bool fast = (__ballot(ok) == 0xFFFFFFFFFFFFFFFFull);

    // constants: slot j holds pre-unit (pbase + (lx^j)) on the fast path,
    // (pbase + j) on the safe path.
    v2f A2[8], B2[8], W2[8], WE2[8];
    #pragma unroll
    for (int j = 0; j < 16; ++j) {
        const int p = pbase + (fast ? (lx ^ j) : j);
        const int o = p * 32 + u;
        const float sg = sigma[o];
        const float ww = w[o];
        A2[j >> 1][j & 1]  = -sg * LOG2E;
        B2[j >> 1][j & 1]  = sg * mu[o] * LOG2E;
        W2[j >> 1][j & 1]  = ww;
        WE2[j >> 1][j & 1] = ww * erev[o];
    }
    const float cmt  = cm[u] * 3.0f;  // cm * ODE_UNFOLDS
    const float gl   = gleak[u];
    const float glvl = gl * vleak[u];

    float osc = 0.0f, osh = 0.0f;
    if (lane < 3) {
        const float sd = std_us[lane];
        osc = output_w[lane] * sd;
        osh = fmaf(output_b[lane], sd, mean_us[lane]);
    }

    const float* wnd_b = wnd_all + (size_t)b * T_LEN * 64 + u * 2;
    float* out_b = out + ((size_t)b * T_LEN) * 3;

#define LDW(tt) (*(const float2*)(wnd_b + (size_t)(tt) * 64))

    float v = 0.0f;
    vbuf[lane] = 0.0f;

    if (fast) {
        // ---------- all-VALU serial loop, deep register prefetch ----------
        // one timestep (3 unfolds) on the current v, using sensory pair wt
        auto do_t = [&](const float2 wt, const int t) {
            const float bnum = glvl + wt.x;
            const float bden = cmt + gl + wt.y + 1e-8f;
            #pragma unroll
            for (int k = 0; k < 3; ++k) {
                float vp[16];
                fast_vp(v, lane, vp);

                // denominators d = 1 + 2^(A*vp+B)
                v2f dv[8];
                #pragma unroll
                for (int j = 0; j < 8; ++j) {
                    const v2f vv = (v2f){vp[2 * j], vp[2 * j + 1]};
                    const v2f arg = A2[j] * vv + B2[j];
                    v2f e;
                    e.x = EXP2F(arg.x);
                    e.y = EXP2F(arg.y);
                    dv[j] = e + 1.0f;
                }

                // batched reciprocals: 2 rcp for all 16 denominators
                float P2[8];
                #pragma unroll
                for (int j = 0; j < 8; ++j)
                    P2[j] = dv[j].x * dv[j].y;
                float P4[4];
                #pragma unroll
                for (int q = 0; q < 4; ++q)
                    P4[q] = P2[2 * q] * P2[2 * q + 1];
                const float P8a = P4[0] * P4[1];
                const float P8b = P4[2] * P4[3];
                const float r8a = __builtin_amdgcn_rcpf(P8a);
                const float r8b = __builtin_amdgcn_rcpf(P8b);
                float t4[4];
                t4[0] = P4[1] * r8a;  t4[1] = P4[0] * r8a;
                t4[2] = P4[3] * r8b;  t4[3] = P4[2] * r8b;
                float t2[8];
                #pragma unroll
                for (int q = 0; q < 4; ++q) {
                    t2[2 * q]     = P2[2 * q + 1] * t4[q];
                    t2[2 * q + 1] = P2[2 * q]     * t4[q];
                }

                v2f wna = (v2f){0.f, 0.f}, wnb = (v2f){0.f, 0.f};
                v2f wda = (v2f){0.f, 0.f}, wdb = (v2f){0.f, 0.f};
                #pragma unroll
                for (int j = 0; j < 8; ++j) {
                    const v2f s =
                        (v2f){dv[j].y, dv[j].x} * (v2f){t2[j], t2[j]};
                    if (j & 1) { wnb = WE2[j] * s + wnb; wdb = W2[j] * s + wdb; }
                    else       { wna = WE2[j] * s + wna; wda = W2[j] * s + wda; }
                }
                const v2f wn2 = wna + wnb;
                const v2f wd2 = wda + wdb;
                const float wnum = pl32_sum(wn2.x + wn2.y);
                const float wden = pl32_sum(wd2.x + wd2.y);

                const float num = fmaf(cmt, v, bnum + wnum);
                v = num * __builtin_amdgcn_rcpf(bden + wden);
            }
            if (lane < 3)
                out_b[t * 3 + lane] = fmaf(v, osc, osh);
        };

        // rotating 4-deep prefetch queue (distance 4 timesteps ≈ 3200 cy)
        float2 w0 = LDW(0), w1 = LDW(1), w2 = LDW(2), w3 = LDW(3);
        for (int t = 0; t < T_LEN; t += 2) {
            const int ta = (t + 4 < T_LEN) ? t + 4 : T_LEN - 1;
            const int tb = (t + 5 < T_LEN) ? t + 5 : T_LEN - 1;
            const float2 n0 = LDW(ta);
            const float2 n1 = LDW(tb);

            do_t(w0, t);
            do_t(w1, t + 1);

            w0 = w2; w1 = w3; w2 = n0; w3 = n1;
        }
    } else {
        // ------------------ known-pass LDS loop (round-3 body) ------------
        float2 wnd = LDW(0);
        for (int t = 0; t < T_LEN; ++t) {
            float2 wnd_n = make_float2(0.0f, 0.0f);
            if (t + 1 < T_LEN)
                wnd_n = LDW(t + 1);

            #pragma unroll
            for (int k = 0; k < 3; ++k) {
                const float4* vb = (const float4*)(vbuf + pbase);
                const float4 q0 = vb[0], q1 = vb[1], q2 = vb[2], q3 = vb[3];
                v2f vp[8];
                vp[0] = (v2f){q0.x, q0.y}; vp[1] = (v2f){q0.z, q0.w};
                vp[2] = (v2f){q1.x, q1.y}; vp[3] = (v2f){q1.z, q1.w};
                vp[4] = (v2f){q2.x, q2.y}; vp[5] = (v2f){q2.z, q2.w};
                vp[6] = (v2f){q3.x, q3.y}; vp[7] = (v2f){q3.z, q3.w};

                v2f wna = (v2f){0.f, 0.f}, wnb = (v2f){0.f, 0.f};
                v2f wda = (v2f){0.f, 0.f}, wdb = (v2f){0.f, 0.f};
                #pragma unroll
                for (int j = 0; j < 8; ++j) {
                    const v2f arg = A2[j] * vp[j] + B2[j];
                    v2f e;
                    e.x = EXP2F(arg.x);
                    e.y = EXP2F(arg.y);
                    const v2f d = e + 1.0f;
                    v2f s;
                    s.x = __builtin_amdgcn_rcpf(d.x);
                    s.y = __builtin_amdgcn_rcpf(d.y);
                    if (j & 1) { wnb = WE2[j] * s + wnb; wdb = W2[j] * s + wdb; }
                    else       { wna = WE2[j] * s + wna; wda = W2[j] * s + wda; }
                }
                const v2f wn2 = wna + wnb;
                const v2f wd2 = wda + wdb;
                float wnum = wn2.x + wn2.y;
                float wden = wd2.x + wd2.y;
                wnum += __shfl_xor(wnum, 32, 64);
                wden += __shfl_xor(wden, 32, 64);

                const float num = fmaf(cmt, v, glvl + wnum + wnd.x);
                const float den = cmt + gl + wden + wnd.y + 1e-8f;
                v = num * __builtin_amdgcn_rcpf(den);
                vbuf[lane] = v;
            }

            if (lane < 3)
                out_b[t * 3 + lane] = fmaf(v, osc, osh);

            wnd = wnd_n;
        }
    }
#undef LDW
}

// ---------------------------------------------------------------------------
extern "C" void kernel_launch(void* const* d_in, const int* in_sizes, int n_in,
                              void* d_out, int out_size, void* d_ws, size_t ws_size,
                              hipStream_t stream) {
    const float* x        = (const float*)d_in[0];
    const float* mean_us  = (const float*)d_in[1];
    const float* std_us   = (const float*)d_in[2];
    const float* pre_w1   = (const float*)d_in[3];
    const float* pre_b1   = (const float*)d_in[4];
    const float* pre_w2   = (const float*)d_in[5];
    const float* pre_b2   = (const float*)d_in[6];
    const float* input_w  = (const float*)d_in[7];
    const float* input_b  = (const float*)d_in[8];
    const float* s_mu     = (const float*)d_in[9];
    const float* s_sigma  = (const float*)d_in[10];
    const float* s_w      = (const float*)d_in[11];
    const float* s_erev   = (const float*)d_in[12];
    const float* mu       = (const float*)d_in[13];
    const float* sigma    = (const float*)d_in[14];
    const float* w        = (const float*)d_in[15];
    const float* erev     = (const float*)d_in[16];
    const float* gleak    = (const float*)d_in[17];
    const float* vleak    = (const float*)d_in[18];
    const float* cm       = (const float*)d_in[19];
    const float* output_w = (const float*)d_in[20];
    const float* output_b = (const float*)d_in[21];

    const int total = BATCH * T_LEN;  // 32768

    float* wnd = (float*)d_ws;  // [B*T, 64] interleaved (wn,wd), 8 MB

    sensory_precompute_kernel<<<(total + 255) / 256, 256, 0, stream>>>(
        x, mean_us, std_us, pre_w1, pre_b1, pre_w2, pre_b2,
        input_w, input_b, s_mu, s_sigma, s_w, s_erev,
        wnd, total);

    ltc_scan_kernel<<<BATCH, 64, 0, stream>>>(
        wnd, mu, sigma, w, erev, gleak, vleak, cm,
        output_w, output_b, mean_us, std_us, (float*)d_out);
}